// Round 9
// baseline (453.471 us; speedup 1.0000x reference)
//
#include <hip/hip_runtime.h>
#include <stdint.h>
#include <stddef.h>

typedef __attribute__((ext_vector_type(8))) short short8;
typedef __attribute__((ext_vector_type(4))) float f32x4;

#define MFMA16(a, b, c) __builtin_amdgcn_mfma_f32_16x16x32_bf16((a), (b), (c), 0, 0, 0)

__device__ __forceinline__ float b2f(short x) {
    unsigned u = ((unsigned)(unsigned short)x) << 16;
    float f; __builtin_memcpy(&f, &u, 4); return f;
}
// round-nearest-even f32->bf16 (used on correctness-sensitive epilogues)
__device__ __forceinline__ short f2b(float f) {
    unsigned u; __builtin_memcpy(&u, &f, 4);
    u = (u + 0x7FFFu + ((u >> 16) & 1u)) >> 16;
    return (short)u;
}
// two f32 -> packed bf16x2 in ONE v_perm (round-half-up via +0x8000):
// result = [bf16(a) low, bf16(b) high]
__device__ __forceinline__ unsigned pack2(float a, float b) {
    unsigned ua, ub; __builtin_memcpy(&ua, &a, 4); __builtin_memcpy(&ub, &b, 4);
    return __builtin_amdgcn_perm(ub + 0x8000u, ua + 0x8000u, 0x07060302u);
}
// 8 contiguous f32 -> bf16x8 (RNE, for the one-time input conversion)
__device__ __forceinline__ short8 load8f(const float* p) {
    const float4 f0 = *(const float4*)p;
    const float4 f1 = *(const float4*)(p + 4);
    short8 r;
    r[0]=f2b(f0.x); r[1]=f2b(f0.y); r[2]=f2b(f0.z); r[3]=f2b(f0.w);
    r[4]=f2b(f1.x); r[5]=f2b(f1.y); r[6]=f2b(f1.z); r[7]=f2b(f1.w);
    return r;
}

// ---------------------------------------------------------------------------
// Fused f32->bf16 converter for up to 3 arrays (one launch). nX = elems/8.
// ---------------------------------------------------------------------------
__global__ __launch_bounds__(256) void cvt3(
    const float* __restrict__ s0, short* __restrict__ d0, int n0,
    const float* __restrict__ s1, short* __restrict__ d1, int n1,
    const float* __restrict__ s2, short* __restrict__ d2, int n2)
{
    int i = blockIdx.x * 256 + threadIdx.x;
    if (i < n0) { *(short8*)(d0 + (size_t)i * 8) = load8f(s0 + (size_t)i * 8); return; }
    i -= n0;
    if (i < n1) { *(short8*)(d1 + (size_t)i * 8) = load8f(s1 + (size_t)i * 8); return; }
    i -= n1;
    if (i < n2) { *(short8*)(d2 + (size_t)i * 8) = load8f(s2 + (size_t)i * 8); }
}

// ---------------------------------------------------------------------------
// QKV GEMM, Q and K sections only (bf16 in/out). Grid (64,8): sec=y>>2, band.
//   sec 0: Q (x0.125) -> Qb[bh][seq][64];  sec 1: K -> Kb[bh][seq][64]
// Block 256 = 4 waves, block tile 128x128, wave 64x64 (m97 gemm_bt pattern).
// ---------------------------------------------------------------------------
__global__ __launch_bounds__(256) void qkv_qk(
    const short* __restrict__ X, const short* __restrict__ W,
    const float* __restrict__ bias,
    short* __restrict__ Qb, short* __restrict__ Kb)
{
    const int tid  = threadIdx.x;
    const int wv   = tid >> 6;
    const int lane = tid & 63;
    const int l15  = lane & 15;
    const int quad = lane >> 4;
    const int m0   = blockIdx.x * 128 + (wv >> 1) * 64;
    const int sec  = blockIdx.y >> 2;                 // 0=Q 1=K
    const int bis  = blockIdx.y & 3;
    const int nbase = sec * 512 + bis * 128;
    const int j0   = (wv & 1) * 64;

    const f32x4 zero = {0.f, 0.f, 0.f, 0.f};
    f32x4 acc[4][4];
#pragma unroll
    for (int i = 0; i < 4; i++)
#pragma unroll
        for (int j = 0; j < 4; j++) acc[i][j] = zero;

    for (int k0 = 0; k0 < 512; k0 += 32) {
        short8 a[4], b[4];
#pragma unroll
        for (int i = 0; i < 4; i++)
            a[i] = *(const short8*)(X + (size_t)(m0 + i * 16 + l15) * 512 + k0 + quad * 8);
#pragma unroll
        for (int j = 0; j < 4; j++)
            b[j] = *(const short8*)(W + (size_t)(nbase + j0 + j * 16 + l15) * 512 + k0 + quad * 8);
#pragma unroll
        for (int i = 0; i < 4; i++)
#pragma unroll
            for (int j = 0; j < 4; j++)
                acc[i][j] = MFMA16(a[i], b[j], acc[i][j]);
    }

#pragma unroll
    for (int j = 0; j < 4; j++) {
        const int jc = bis * 128 + j0 + j * 16 + l15;   // 0..511 in section
        const float bs = bias[sec * 512 + jc];
        const int hl = jc >> 6, d = jc & 63;
#pragma unroll
        for (int i = 0; i < 4; i++) {
#pragma unroll
            for (int r = 0; r < 4; r++) {
                const int m = m0 + i * 16 + quad * 4 + r;
                const int bb = m >> 12, seq = m & 4095;
                const int bh = bb * 8 + hl;
                const float v = acc[i][j][r] + bs;
                if (sec == 0)
                    Qb[((size_t)bh * 4096 + seq) * 64 + d] = f2b(v * 0.125f);
                else
                    Kb[((size_t)bh * 4096 + seq) * 64 + d] = f2b(v);
            }
        }
    }
}

// ---------------------------------------------------------------------------
// QKV GEMM, V section, with LDS-transposed epilogue: Vb[bh][d][seq].
// Round-8's V epilogue was 64 scalar 2B global stores/thread at 8KB stride
// (~32x write amplification). Now: C-tile -> packed b64 LDS writes ->
// coalesced b128 global stores along seq. Grid (64,4), block 256.
// ---------------------------------------------------------------------------
__global__ __launch_bounds__(256) void qkv_v(
    const short* __restrict__ X, const short* __restrict__ W,
    const float* __restrict__ bias, short* __restrict__ Vb)
{
    __shared__ short sT[128][132];   // [jc][seq_local], stride 66 dw (odd-ish banking)

    const int tid  = threadIdx.x;
    const int wv   = tid >> 6;
    const int lane = tid & 63;
    const int l15  = lane & 15;
    const int quad = lane >> 4;
    const int m0   = blockIdx.x * 128 + (wv >> 1) * 64;
    const int bis  = blockIdx.y;
    const int nbase = 1024 + bis * 128;
    const int j0   = (wv & 1) * 64;

    const f32x4 zero = {0.f, 0.f, 0.f, 0.f};
    f32x4 acc[4][4];
#pragma unroll
    for (int i = 0; i < 4; i++)
#pragma unroll
        for (int j = 0; j < 4; j++) acc[i][j] = zero;

    for (int k0 = 0; k0 < 512; k0 += 32) {
        short8 a[4], b[4];
#pragma unroll
        for (int i = 0; i < 4; i++)
            a[i] = *(const short8*)(X + (size_t)(m0 + i * 16 + l15) * 512 + k0 + quad * 8);
#pragma unroll
        for (int j = 0; j < 4; j++)
            b[j] = *(const short8*)(W + (size_t)(nbase + j0 + j * 16 + l15) * 512 + k0 + quad * 8);
#pragma unroll
        for (int i = 0; i < 4; i++)
#pragma unroll
            for (int j = 0; j < 4; j++)
                acc[i][j] = MFMA16(a[i], b[j], acc[i][j]);
    }

    // pack 4 consecutive seq (C regs r=0..3) into one b64 LDS write
#pragma unroll
    for (int j = 0; j < 4; j++) {
        const int jcl = j0 + j * 16 + l15;             // 0..127
        const float bs = bias[nbase + jcl];
#pragma unroll
        for (int i = 0; i < 4; i++) {
            uint2 w;
            w.x = pack2(acc[i][j][0] + bs, acc[i][j][1] + bs);
            w.y = pack2(acc[i][j][2] + bs, acc[i][j][3] + bs);
            *(uint2*)&sT[jcl][(wv >> 1) * 64 + i * 16 + quad * 4] = w;
        }
    }
    __syncthreads();

    // coalesced store: thread -> one (jc, 64-seq half), 8 x b128 along seq
    const int jcl = tid >> 1, half = tid & 1;
    const int hl = (bis * 128 + jcl) >> 6;             // head 0..7
    const int d  = jcl & 63;
    const int bb = (blockIdx.x * 128) >> 12;
    const int seq0 = ((blockIdx.x * 128) & 4095) + half * 64;
    short* dst = Vb + ((size_t)(bb * 8 + hl) * 64 + d) * 4096 + seq0;
#pragma unroll
    for (int u = 0; u < 8; u++)
        *(short8*)(dst + u * 8) = *(const short8*)&sT[jcl][half * 64 + u * 8];
}

// ---------------------------------------------------------------------------
// Flash attention, BARRIER-FREE: K/V MFMA fragments read straight from global
// (L2 — consecutive blocks share bh, so the per-XCD working set fits the 4MB
// L2). LDS holds only the wave-private P round-trip (sP), ordered by
// __threadfence_block. Transposed compute (S^T, O^T) as round 8.
// Grid (64, 16, nsplit): z splits the keys; with no-max streaming softmax the
// partials combine exactly: O = (l0*O0 + l1*O1)/(l0+l1).
// Each split writes its own-l-normalized O (bf16, attn layout) + l (f32).
// nsplit==1 (lbuf==nullptr): writes final attn directly.
// ---------------------------------------------------------------------------
__global__ __launch_bounds__(128) void flash_attn(
    const short* __restrict__ Q, const short* __restrict__ K,
    const short* __restrict__ V, short* __restrict__ PO0,
    short* __restrict__ PO1, float* __restrict__ lbuf, int ktiles)
{
    __shared__ short sP[2][2][16][72];   // [wave][group][query][key] (+pad, 16B rows)

    const int tid  = threadIdx.x;
    const int wv   = tid >> 6;
    const int lane = tid & 63;
    const int l15  = lane & 15;
    const int quad = lane >> 4;
    const int bh = blockIdx.y;
    const int b = bh >> 3, h = bh & 7;
    const int qw = blockIdx.x * 64 + wv * 32;
    const int ks = blockIdx.z;
    const int key0 = ks * ktiles * 64;

    const short* Qb = Q + (size_t)bh * 4096 * 64;
    const short* Kb = K + (size_t)bh * 4096 * 64;
    const short* Vb = V + (size_t)bh * 64 * 4096;

    // Q fragments (B-operand): B[k=d][n=query l15]
    const short8 aq00 = *(const short8*)(Qb + (size_t)(qw + l15) * 64 + quad * 8);
    const short8 aq01 = *(const short8*)(Qb + (size_t)(qw + l15) * 64 + 32 + quad * 8);
    const short8 aq10 = *(const short8*)(Qb + (size_t)(qw + 16 + l15) * 64 + quad * 8);
    const short8 aq11 = *(const short8*)(Qb + (size_t)(qw + 16 + l15) * 64 + 32 + quad * 8);

    const f32x4 zero = {0.f, 0.f, 0.f, 0.f};
    f32x4 o0[4], o1[4];
    float l0 = 0.f, l1 = 0.f;
#pragma unroll
    for (int r = 0; r < 4; r++) { o0[r] = zero; o1[r] = zero; }

    for (int kt = 0; kt < ktiles; ++kt) {
        const int k0 = key0 + kt * 64;

        // S^T = K x Q^T : A=K[key][d] frags straight from global
        f32x4 ST0[4], ST1[4];
#pragma unroll
        for (int c = 0; c < 4; c++) {
            const short* kp = Kb + (size_t)(k0 + c * 16 + l15) * 64 + quad * 8;
            const short8 bk0 = *(const short8*)kp;
            const short8 bk1 = *(const short8*)(kp + 32);
            ST0[c] = MFMA16(bk1, aq01, MFMA16(bk0, aq00, zero));
            ST1[c] = MFMA16(bk1, aq11, MFMA16(bk0, aq10, zero));
        }

        // exp + packed b64 sP stores (lane's 4 regs = 4 consecutive keys)
#pragma unroll
        for (int c = 0; c < 4; c++) {
            const float p0 = __expf(ST0[c][0]), p1 = __expf(ST0[c][1]);
            const float p2 = __expf(ST0[c][2]), p3 = __expf(ST0[c][3]);
            l0 += (p0 + p1) + (p2 + p3);
            uint2 w; w.x = pack2(p0, p1); w.y = pack2(p2, p3);
            *(uint2*)&sP[wv][0][l15][c * 16 + quad * 4] = w;
            const float r0 = __expf(ST1[c][0]), r1 = __expf(ST1[c][1]);
            const float r2 = __expf(ST1[c][2]), r3 = __expf(ST1[c][3]);
            l1 += (r0 + r1) + (r2 + r3);
            uint2 v; v.x = pack2(r0, r1); v.y = pack2(r2, r3);
            *(uint2*)&sP[wv][1][l15][c * 16 + quad * 4] = v;
        }
        __threadfence_block();   // wave-private sP: write -> read ordering

        const short8 bp00 = *(const short8*)&sP[wv][0][l15][quad * 8];
        const short8 bp01 = *(const short8*)&sP[wv][0][l15][32 + quad * 8];
        const short8 bp10 = *(const short8*)&sP[wv][1][l15][quad * 8];
        const short8 bp11 = *(const short8*)&sP[wv][1][l15][32 + quad * 8];

        // O^T += V^T x P^T : A=V^T[d][key] frags straight from global
#pragma unroll
        for (int td = 0; td < 4; td++) {
            const short* vp = Vb + (size_t)(td * 16 + l15) * 4096 + k0;
            const short8 bv0 = *(const short8*)(vp + quad * 8);
            const short8 bv1 = *(const short8*)(vp + 32 + quad * 8);
            o0[td] = MFMA16(bv0, bp00, o0[td]);
            o0[td] = MFMA16(bv1, bp01, o0[td]);
            o1[td] = MFMA16(bv0, bp10, o1[td]);
            o1[td] = MFMA16(bv1, bp11, o1[td]);
        }
        __threadfence_block();   // keep next tile's sP writes after these reads
    }

    // full row sums: lanes {l15, +16, +32, +48} hold quad-partials
    l0 += __shfl_xor(l0, 16); l0 += __shfl_xor(l0, 32);
    l1 += __shfl_xor(l1, 16); l1 += __shfl_xor(l1, 32);
    const float inv0 = 1.f / fmaxf(l0, 1e-30f);
    const float inv1 = 1.f / fmaxf(l1, 1e-30f);

    short* PO = (ks == 0) ? PO0 : PO1;
    // O^T: lane regs = 4 consecutive d for query l15 -> packed uint2 stores
#pragma unroll
    for (int td = 0; td < 4; td++) {
        uint2 w0, w1;
        w0.x = pack2(o0[td][0] * inv0, o0[td][1] * inv0);
        w0.y = pack2(o0[td][2] * inv0, o0[td][3] * inv0);
        w1.x = pack2(o1[td][0] * inv1, o1[td][1] * inv1);
        w1.y = pack2(o1[td][2] * inv1, o1[td][3] * inv1);
        const int col = h * 64 + td * 16 + quad * 4;
        *(uint2*)(PO + ((size_t)b * 4096 + qw + l15) * 512 + col) = w0;
        *(uint2*)(PO + ((size_t)b * 4096 + qw + 16 + l15) * 512 + col) = w1;
    }
    if (lbuf && quad == 0) {
        lbuf[((size_t)ks * 16 + bh) * 4096 + qw + l15] = l0;
        lbuf[((size_t)ks * 16 + bh) * 4096 + qw + 16 + l15] = l1;
    }
}

// ---------------------------------------------------------------------------
// Combine the 2 key-split partials (in-place over PO1 = attn region):
// attn = (l0*O0 + l1*O1) / (l0+l1). Element-wise, memory-bound.
// ---------------------------------------------------------------------------
__global__ __launch_bounds__(256) void combine(
    const short* __restrict__ PO0, short* __restrict__ PO1,
    const float* __restrict__ L)
{
    const int i = blockIdx.x * 256 + threadIdx.x;   // 0..524287
    const size_t flat = (size_t)i * 8;
    const int col = (int)(flat & 511);
    const int q   = (int)((flat >> 9) & 4095);
    const int b   = (int)(flat >> 21);
    const int bh  = b * 8 + (col >> 6);
    const float l0 = L[(size_t)bh * 4096 + q];
    const float l1 = L[(size_t)65536 + (size_t)bh * 4096 + q];
    const float inv = 1.f / (l0 + l1);
    const float w0 = l0 * inv, w1 = l1 * inv;
    const short8 a = *(const short8*)(PO0 + flat);
    const short8 c = *(const short8*)(PO1 + flat);
    short8 r;
#pragma unroll
    for (int k = 0; k < 8; k++) r[k] = f2b(w0 * b2f(a[k]) + w1 * b2f(c[k]));
    *(short8*)(PO1 + flat) = r;
}

// ---------------------------------------------------------------------------
// Projection piece: dst[m_local][n] = attn[m_base+m_local] @ pw^T + proj_b.
// attn bf16, pw bf16, bias f32, dst f32. Grid (rows/128, 4).
// ---------------------------------------------------------------------------
__global__ __launch_bounds__(256) void proj_piece(
    const short* __restrict__ A, const short* __restrict__ W,
    const float* __restrict__ bias, float* __restrict__ dst, int m_base)
{
    const int tid  = threadIdx.x;
    const int wv   = tid >> 6;
    const int lane = tid & 63;
    const int l15  = lane & 15;
    const int quad = lane >> 4;
    const int m0 = blockIdx.x * 128 + (wv >> 1) * 64;
    const int n0 = blockIdx.y * 128 + (wv & 1) * 64;

    const f32x4 zero = {0.f, 0.f, 0.f, 0.f};
    f32x4 acc[4][4];
#pragma unroll
    for (int i = 0; i < 4; i++)
#pragma unroll
        for (int j = 0; j < 4; j++) acc[i][j] = zero;

    for (int k0 = 0; k0 < 512; k0 += 32) {
        short8 a[4], b[4];
#pragma unroll
        for (int i = 0; i < 4; i++)
            a[i] = *(const short8*)(A + (size_t)(m_base + m0 + i * 16 + l15) * 512 + k0 + quad * 8);
#pragma unroll
        for (int j = 0; j < 4; j++)
            b[j] = *(const short8*)(W + (size_t)(n0 + j * 16 + l15) * 512 + k0 + quad * 8);
#pragma unroll
        for (int i = 0; i < 4; i++)
#pragma unroll
            for (int j = 0; j < 4; j++)
                acc[i][j] = MFMA16(a[i], b[j], acc[i][j]);
    }

#pragma unroll
    for (int j = 0; j < 4; j++) {
        const int n = n0 + j * 16 + l15;
        const float bs = bias[n];
#pragma unroll
        for (int i = 0; i < 4; i++) {
#pragma unroll
            for (int r = 0; r < 4; r++) {
                const int m = m0 + i * 16 + quad * 4 + r;
                dst[(size_t)m * 512 + n] = acc[i][j][r] + bs;
            }
        }
    }
}

// ---------------------------------------------------------------------------
// Memory plan:
//   d_out [0,8M):    xb (x bf16) -> PO0 (flash split 0) -> proj0 output
//   d_out [8M,9.5M): wb (qkv_w bf16), dead once flash writes attn/PO1
//   d_out [8M,16M):  PO1 / attn (combine runs in-place) -> proj1 output (copy)
//   ws [0,8M) Qf (later proj1 stage) | [8M,16M) Kf | [16M,24M) Vf
//   ws [24M,24.5M) lbuf | [24.5M,25M) pwb          (needs ws >= 25 MB)
// Fallback (ws < 25 MB): nsplit=1 flash (round-8-proven placement).
// ---------------------------------------------------------------------------
extern "C" void kernel_launch(void* const* d_in, const int* in_sizes, int n_in,
                              void* d_out, int out_size, void* d_ws, size_t ws_size,
                              hipStream_t stream)
{
    const float* x      = (const float*)d_in[0];   // [2,4096,512] f32
    const float* qkv_w  = (const float*)d_in[1];   // [1536,512]   f32
    const float* qkv_b  = (const float*)d_in[2];   // [1536]       f32
    const float* proj_w = (const float*)d_in[3];   // [512,512]    f32
    const float* proj_b = (const float*)d_in[4];   // [512]        f32

    const size_t MB = 1024 * 1024;
    short* xb   = (short*)d_out;
    short* wb   = (short*)d_out + 4 * MB;
    short* attn = (short*)d_out + 4 * MB;
    float* out  = (float*)d_out;

    short* Qf = (short*)d_ws;
    short* Kf = Qf + (size_t)16 * 4096 * 64;
    short* Vf = Kf + (size_t)16 * 4096 * 64;       // [bh][64][4096]

    if (ws_size >= 25 * MB) {
        float* lbuf = (float*)((char*)d_ws + 24 * MB);
        short* pwb  = (short*)((char*)d_ws + 24 * MB + 512 * 1024);
        cvt3<<<2560, 256, 0, stream>>>(x, xb, 524288, qkv_w, wb, 98304, proj_w, pwb, 32768);
        qkv_qk<<<dim3(64, 8), 256, 0, stream>>>(xb, wb, qkv_b, Qf, Kf);
        qkv_v <<<dim3(64, 4), 256, 0, stream>>>(xb, wb, qkv_b, Vf);
        flash_attn<<<dim3(64, 16, 2), 128, 0, stream>>>(Qf, Kf, Vf, (short*)d_out, attn, lbuf, 32);
        combine<<<2048, 256, 0, stream>>>((const short*)d_out, attn, lbuf);
        proj_piece<<<dim3(32, 4), 256, 0, stream>>>(attn, pwb, proj_b, out, 0);
        proj_piece<<<dim3(32, 4), 256, 0, stream>>>(attn, pwb, proj_b, (float*)d_ws, 4096);
        hipMemcpyAsync((char*)d_out + 8 * MB, d_ws, 8 * MB,
                       hipMemcpyDeviceToDevice, stream);
    } else {
        short* pwb = Kf;   // K region, dead after flash
        cvt3<<<2432, 256, 0, stream>>>(x, xb, 524288, qkv_w, wb, 98304,
                                       nullptr, nullptr, 0);
        qkv_qk<<<dim3(64, 8), 256, 0, stream>>>(xb, wb, qkv_b, Qf, Kf);
        qkv_v <<<dim3(64, 4), 256, 0, stream>>>(xb, wb, qkv_b, Vf);
        flash_attn<<<dim3(64, 16, 1), 128, 0, stream>>>(Qf, Kf, Vf, attn, attn, nullptr, 64);
        cvt3<<<128, 256, 0, stream>>>(proj_w, pwb, 32768, nullptr, nullptr, 0,
                                      nullptr, nullptr, 0);
        proj_piece<<<dim3(32, 4), 256, 0, stream>>>(attn, pwb, proj_b, out, 0);
        proj_piece<<<dim3(32, 4), 256, 0, stream>>>(attn, pwb, proj_b, (float*)d_ws, 4096);
        hipMemcpyAsync((char*)d_out + 8 * MB, d_ws, 8 * MB,
                       hipMemcpyDeviceToDevice, stream);
    }
}

// Round 10
// 281.745 us; speedup vs baseline: 1.6095x; 1.6095x over previous
//
#include <hip/hip_runtime.h>
#include <stdint.h>
#include <stddef.h>

typedef __attribute__((ext_vector_type(8))) short short8;
typedef __attribute__((ext_vector_type(4))) float f32x4;

#define MFMA16(a, b, c) __builtin_amdgcn_mfma_f32_16x16x32_bf16((a), (b), (c), 0, 0, 0)

__device__ __forceinline__ float b2f(short x) {
    unsigned u = ((unsigned)(unsigned short)x) << 16;
    float f; __builtin_memcpy(&f, &u, 4); return f;
}
// round-nearest-even f32->bf16
__device__ __forceinline__ short f2b(float f) {
    unsigned u; __builtin_memcpy(&u, &f, 4);
    u = (u + 0x7FFFu + ((u >> 16) & 1u)) >> 16;
    return (short)u;
}
// two f32 -> packed bf16x2 in ONE v_perm (round-half-up via +0x8000)
__device__ __forceinline__ unsigned pack2(float a, float b) {
    unsigned ua, ub; __builtin_memcpy(&ua, &a, 4); __builtin_memcpy(&ub, &b, 4);
    return __builtin_amdgcn_perm(ub + 0x8000u, ua + 0x8000u, 0x07060302u);
}
// 8 contiguous f32 -> bf16x8 (RNE)
__device__ __forceinline__ short8 load8f(const float* p) {
    const float4 f0 = *(const float4*)p;
    const float4 f1 = *(const float4*)(p + 4);
    short8 r;
    r[0]=f2b(f0.x); r[1]=f2b(f0.y); r[2]=f2b(f0.z); r[3]=f2b(f0.w);
    r[4]=f2b(f1.x); r[5]=f2b(f1.y); r[6]=f2b(f1.z); r[7]=f2b(f1.w);
    return r;
}

// ---------------------------------------------------------------------------
// Fused f32->bf16 converter for up to 3 arrays. nX = elems/8.
// ---------------------------------------------------------------------------
__global__ __launch_bounds__(256) void cvt3(
    const float* __restrict__ s0, short* __restrict__ d0, int n0,
    const float* __restrict__ s1, short* __restrict__ d1, int n1,
    const float* __restrict__ s2, short* __restrict__ d2, int n2)
{
    int i = blockIdx.x * 256 + threadIdx.x;
    if (i < n0) { *(short8*)(d0 + (size_t)i * 8) = load8f(s0 + (size_t)i * 8); return; }
    i -= n0;
    if (i < n1) { *(short8*)(d1 + (size_t)i * 8) = load8f(s1 + (size_t)i * 8); return; }
    i -= n1;
    if (i < n2) { *(short8*)(d2 + (size_t)i * 8) = load8f(s2 + (size_t)i * 8); }
}

// ---------------------------------------------------------------------------
// QKV GEMM, Q and K sections (bf16 in/out). Grid (64,8): sec=y>>2, band.
//   sec 0: Q (x0.125) -> Qb[bh][seq][64];  sec 1: K -> Kb[bh][seq][64]
// ---------------------------------------------------------------------------
__global__ __launch_bounds__(256) void qkv_qk(
    const short* __restrict__ X, const short* __restrict__ W,
    const float* __restrict__ bias,
    short* __restrict__ Qb, short* __restrict__ Kb)
{
    const int tid  = threadIdx.x;
    const int wv   = tid >> 6;
    const int lane = tid & 63;
    const int l15  = lane & 15;
    const int quad = lane >> 4;
    const int m0   = blockIdx.x * 128 + (wv >> 1) * 64;
    const int sec  = blockIdx.y >> 2;                 // 0=Q 1=K
    const int bis  = blockIdx.y & 3;
    const int nbase = sec * 512 + bis * 128;
    const int j0   = (wv & 1) * 64;

    const f32x4 zero = {0.f, 0.f, 0.f, 0.f};
    f32x4 acc[4][4];
#pragma unroll
    for (int i = 0; i < 4; i++)
#pragma unroll
        for (int j = 0; j < 4; j++) acc[i][j] = zero;

    for (int k0 = 0; k0 < 512; k0 += 32) {
        short8 a[4], b[4];
#pragma unroll
        for (int i = 0; i < 4; i++)
            a[i] = *(const short8*)(X + (size_t)(m0 + i * 16 + l15) * 512 + k0 + quad * 8);
#pragma unroll
        for (int j = 0; j < 4; j++)
            b[j] = *(const short8*)(W + (size_t)(nbase + j0 + j * 16 + l15) * 512 + k0 + quad * 8);
#pragma unroll
        for (int i = 0; i < 4; i++)
#pragma unroll
            for (int j = 0; j < 4; j++)
                acc[i][j] = MFMA16(a[i], b[j], acc[i][j]);
    }

#pragma unroll
    for (int j = 0; j < 4; j++) {
        const int jc = bis * 128 + j0 + j * 16 + l15;   // 0..511 in section
        const float bs = bias[sec * 512 + jc];
        const int hl = jc >> 6, d = jc & 63;
#pragma unroll
        for (int i = 0; i < 4; i++) {
#pragma unroll
            for (int r = 0; r < 4; r++) {
                const int m = m0 + i * 16 + quad * 4 + r;
                const int bb = m >> 12, seq = m & 4095;
                const int bh = bb * 8 + hl;
                const float v = acc[i][j][r] + bs;
                if (sec == 0)
                    Qb[((size_t)bh * 4096 + seq) * 64 + d] = f2b(v * 0.125f);
                else
                    Kb[((size_t)bh * 4096 + seq) * 64 + d] = f2b(v);
            }
        }
    }
}

// ---------------------------------------------------------------------------
// QKV GEMM, V section, LDS-transposed epilogue -> Vb[bh][d][seq] coalesced.
// ---------------------------------------------------------------------------
__global__ __launch_bounds__(256) void qkv_v(
    const short* __restrict__ X, const short* __restrict__ W,
    const float* __restrict__ bias, short* __restrict__ Vb)
{
    __shared__ short sT[128][132];

    const int tid  = threadIdx.x;
    const int wv   = tid >> 6;
    const int lane = tid & 63;
    const int l15  = lane & 15;
    const int quad = lane >> 4;
    const int m0   = blockIdx.x * 128 + (wv >> 1) * 64;
    const int bis  = blockIdx.y;
    const int nbase = 1024 + bis * 128;
    const int j0   = (wv & 1) * 64;

    const f32x4 zero = {0.f, 0.f, 0.f, 0.f};
    f32x4 acc[4][4];
#pragma unroll
    for (int i = 0; i < 4; i++)
#pragma unroll
        for (int j = 0; j < 4; j++) acc[i][j] = zero;

    for (int k0 = 0; k0 < 512; k0 += 32) {
        short8 a[4], b[4];
#pragma unroll
        for (int i = 0; i < 4; i++)
            a[i] = *(const short8*)(X + (size_t)(m0 + i * 16 + l15) * 512 + k0 + quad * 8);
#pragma unroll
        for (int j = 0; j < 4; j++)
            b[j] = *(const short8*)(W + (size_t)(nbase + j0 + j * 16 + l15) * 512 + k0 + quad * 8);
#pragma unroll
        for (int i = 0; i < 4; i++)
#pragma unroll
            for (int j = 0; j < 4; j++)
                acc[i][j] = MFMA16(a[i], b[j], acc[i][j]);
    }

#pragma unroll
    for (int j = 0; j < 4; j++) {
        const int jcl = j0 + j * 16 + l15;             // 0..127
        const float bs = bias[nbase + jcl];
#pragma unroll
        for (int i = 0; i < 4; i++) {
            uint2 w;
            w.x = pack2(acc[i][j][0] + bs, acc[i][j][1] + bs);
            w.y = pack2(acc[i][j][2] + bs, acc[i][j][3] + bs);
            *(uint2*)&sT[jcl][(wv >> 1) * 64 + i * 16 + quad * 4] = w;
        }
    }
    __syncthreads();

    const int jcl = tid >> 1, half = tid & 1;
    const int hl = (bis * 128 + jcl) >> 6;
    const int d  = jcl & 63;
    const int bb = (blockIdx.x * 128) >> 12;
    const int seq0 = ((blockIdx.x * 128) & 4095) + half * 64;
    short* dst = Vb + ((size_t)(bb * 8 + hl) * 64 + d) * 4096 + seq0;
#pragma unroll
    for (int u = 0; u < 8; u++)
        *(short8*)(dst + u * 8) = *(const short8*)&sT[jcl][half * 64 + u * 8];
}

// ---------------------------------------------------------------------------
// Flash attention: LDS-staged K/V (round-8 structure — global-direct reads
// proven 2x WORSE in round 9: address divergence fragments wave loads into
// ~16 L2 transactions each), transposed compute (S^T/O^T), packed sP,
// register prefetch of next tile.
// NEW: 4-wave blocks (128 q/block) + split-K=2 -> grid (32,16,2) = 1024
// blocks = 4 blocks/CU, LDS 36.9 KB = exactly 4 blocks/CU resident ->
// 16 waves/CU (~50% occ) vs round-8's 8 (19%). Same per-work LDS traffic;
// the extra co-residency overlaps the LDS/VALU/MFMA pipes.
// Split partials (no-max softmax): O = (l0*O0 + l1*O1)/(l0+l1), exact.
// ---------------------------------------------------------------------------
__global__ __launch_bounds__(256) void flash_attn(
    const short* __restrict__ Q, const short* __restrict__ K,
    const short* __restrict__ V, short* __restrict__ PO0,
    short* __restrict__ PO1, float* __restrict__ lbuf, int ktiles)
{
    __shared__ short sK[64][72];
    __shared__ short sV[64][72];          // sV[d][key]
    __shared__ short sP[4][2][16][72];    // [wave][group][query][key]

    const int tid  = threadIdx.x;
    const int wv   = tid >> 6;
    const int lane = tid & 63;
    const int l15  = lane & 15;
    const int quad = lane >> 4;
    const int bh = blockIdx.y;
    const int b = bh >> 3, h = bh & 7;
    const int qw = blockIdx.x * 128 + wv * 32;   // wave's first query
    const int ks = blockIdx.z;
    const int key0 = ks * ktiles * 64;

    const short* Qb = Q + (size_t)bh * 4096 * 64;
    const short* Kb = K + (size_t)bh * 4096 * 64;
    const short* Vb = V + (size_t)bh * 64 * 4096;

    // Q fragments (B-operand): B[k=d][n=query l15]
    const short8 aq00 = *(const short8*)(Qb + (size_t)(qw + l15) * 64 + quad * 8);
    const short8 aq01 = *(const short8*)(Qb + (size_t)(qw + l15) * 64 + 32 + quad * 8);
    const short8 aq10 = *(const short8*)(Qb + (size_t)(qw + 16 + l15) * 64 + quad * 8);
    const short8 aq11 = *(const short8*)(Qb + (size_t)(qw + 16 + l15) * 64 + 32 + quad * 8);

    const f32x4 zero = {0.f, 0.f, 0.f, 0.f};
    f32x4 o0[4], o1[4];
    float l0 = 0.f, l1 = 0.f;
#pragma unroll
    for (int r = 0; r < 4; r++) { o0[r] = zero; o1[r] = zero; }

    // staging: 1024 16B-chunks (K:512, V:512) over 256 threads -> 2+2 each
    int srow[2], scb[2];
#pragma unroll
    for (int i = 0; i < 2; i++) {
        const int c = tid + i * 256;
        srow[i] = c >> 3; scb[i] = (c & 7) * 8;
    }

    short8 pk[2], pv[2];
#pragma unroll
    for (int i = 0; i < 2; i++) {
        pk[i] = *(const short8*)(Kb + (size_t)(key0 + srow[i]) * 64 + scb[i]);
        pv[i] = *(const short8*)(Vb + (size_t)srow[i] * 4096 + key0 + scb[i]);
    }

    for (int kt = 0; kt < ktiles; ++kt) {
        const int k0 = key0 + kt * 64;
        __syncthreads();               // all waves done reading prev tile
#pragma unroll
        for (int i = 0; i < 2; i++) {
            *(short8*)&sK[srow[i]][scb[i]] = pk[i];
            *(short8*)&sV[srow[i]][scb[i]] = pv[i];
        }
        __syncthreads();               // staging visible

        if (kt + 1 < ktiles) {         // prefetch next tile (overlaps compute)
            const int k0n = k0 + 64;
#pragma unroll
            for (int i = 0; i < 2; i++) {
                pk[i] = *(const short8*)(Kb + (size_t)(k0n + srow[i]) * 64 + scb[i]);
                pv[i] = *(const short8*)(Vb + (size_t)srow[i] * 4096 + k0n + scb[i]);
            }
        }

        // S^T = K x Q^T (A=K[key][d] frags from LDS)
        f32x4 ST0[4], ST1[4];
#pragma unroll
        for (int c = 0; c < 4; c++) {
            const short8 bk0 = *(const short8*)&sK[c * 16 + l15][quad * 8];
            const short8 bk1 = *(const short8*)&sK[c * 16 + l15][32 + quad * 8];
            ST0[c] = MFMA16(bk1, aq01, MFMA16(bk0, aq00, zero));
            ST1[c] = MFMA16(bk1, aq11, MFMA16(bk0, aq10, zero));
        }

        // exp + packed b64 sP stores (lane's 4 regs = 4 consecutive keys)
#pragma unroll
        for (int c = 0; c < 4; c++) {
            const float p0 = __expf(ST0[c][0]), p1 = __expf(ST0[c][1]);
            const float p2 = __expf(ST0[c][2]), p3 = __expf(ST0[c][3]);
            l0 += (p0 + p1) + (p2 + p3);
            uint2 w; w.x = pack2(p0, p1); w.y = pack2(p2, p3);
            *(uint2*)&sP[wv][0][l15][c * 16 + quad * 4] = w;
            const float r0 = __expf(ST1[c][0]), r1 = __expf(ST1[c][1]);
            const float r2 = __expf(ST1[c][2]), r3 = __expf(ST1[c][3]);
            l1 += (r0 + r1) + (r2 + r3);
            uint2 v; v.x = pack2(r0, r1); v.y = pack2(r2, r3);
            *(uint2*)&sP[wv][1][l15][c * 16 + quad * 4] = v;
        }
        __threadfence_block();         // wave-private sP: write -> read order

        const short8 bp00 = *(const short8*)&sP[wv][0][l15][quad * 8];
        const short8 bp01 = *(const short8*)&sP[wv][0][l15][32 + quad * 8];
        const short8 bp10 = *(const short8*)&sP[wv][1][l15][quad * 8];
        const short8 bp11 = *(const short8*)&sP[wv][1][l15][32 + quad * 8];

        // O^T += V^T x P^T (A=V^T[d][key] frags from LDS)
#pragma unroll
        for (int td = 0; td < 4; td++) {
            const short8 bv0 = *(const short8*)&sV[td * 16 + l15][quad * 8];
            const short8 bv1 = *(const short8*)&sV[td * 16 + l15][32 + quad * 8];
            o0[td] = MFMA16(bv0, bp00, o0[td]);
            o0[td] = MFMA16(bv1, bp01, o0[td]);
            o1[td] = MFMA16(bv0, bp10, o1[td]);
            o1[td] = MFMA16(bv1, bp11, o1[td]);
        }
    }

    l0 += __shfl_xor(l0, 16); l0 += __shfl_xor(l0, 32);
    l1 += __shfl_xor(l1, 16); l1 += __shfl_xor(l1, 32);
    const float inv0 = 1.f / fmaxf(l0, 1e-30f);
    const float inv1 = 1.f / fmaxf(l1, 1e-30f);

    short* PO = (ks == 0) ? PO0 : PO1;
#pragma unroll
    for (int td = 0; td < 4; td++) {
        uint2 w0, w1;
        w0.x = pack2(o0[td][0] * inv0, o0[td][1] * inv0);
        w0.y = pack2(o0[td][2] * inv0, o0[td][3] * inv0);
        w1.x = pack2(o1[td][0] * inv1, o1[td][1] * inv1);
        w1.y = pack2(o1[td][2] * inv1, o1[td][3] * inv1);
        const int col = h * 64 + td * 16 + quad * 4;
        *(uint2*)(PO + ((size_t)b * 4096 + qw + l15) * 512 + col) = w0;
        *(uint2*)(PO + ((size_t)b * 4096 + qw + 16 + l15) * 512 + col) = w1;
    }
    if (lbuf && quad == 0) {
        lbuf[((size_t)ks * 16 + bh) * 4096 + qw + l15] = l0;
        lbuf[((size_t)ks * 16 + bh) * 4096 + qw + 16 + l15] = l1;
    }
}

// ---------------------------------------------------------------------------
// Combine the 2 key-split partials (in-place over PO1 = attn region):
// attn = (l0*O0 + l1*O1) / (l0+l1). Element-wise, memory-bound.
// ---------------------------------------------------------------------------
__global__ __launch_bounds__(256) void combine(
    const short* __restrict__ PO0, short* __restrict__ PO1,
    const float* __restrict__ L)
{
    const int i = blockIdx.x * 256 + threadIdx.x;   // 0..524287
    const size_t flat = (size_t)i * 8;
    const int col = (int)(flat & 511);
    const int q   = (int)((flat >> 9) & 4095);
    const int b   = (int)(flat >> 21);
    const int bh  = b * 8 + (col >> 6);
    const float l0 = L[(size_t)bh * 4096 + q];
    const float l1 = L[(size_t)65536 + (size_t)bh * 4096 + q];
    const float inv = 1.f / (l0 + l1);
    const float w0 = l0 * inv, w1 = l1 * inv;
    const short8 a = *(const short8*)(PO0 + flat);
    const short8 c = *(const short8*)(PO1 + flat);
    short8 r;
#pragma unroll
    for (int k = 0; k < 8; k++) r[k] = f2b(w0 * b2f(a[k]) + w1 * b2f(c[k]));
    *(short8*)(PO1 + flat) = r;
}

// ---------------------------------------------------------------------------
// Projection piece: dst[m_local][n] = attn[m_base+m_local] @ pw^T + proj_b.
// ---------------------------------------------------------------------------
__global__ __launch_bounds__(256) void proj_piece(
    const short* __restrict__ A, const short* __restrict__ W,
    const float* __restrict__ bias, float* __restrict__ dst, int m_base)
{
    const int tid  = threadIdx.x;
    const int wv   = tid >> 6;
    const int lane = tid & 63;
    const int l15  = lane & 15;
    const int quad = lane >> 4;
    const int m0 = blockIdx.x * 128 + (wv >> 1) * 64;
    const int n0 = blockIdx.y * 128 + (wv & 1) * 64;

    const f32x4 zero = {0.f, 0.f, 0.f, 0.f};
    f32x4 acc[4][4];
#pragma unroll
    for (int i = 0; i < 4; i++)
#pragma unroll
        for (int j = 0; j < 4; j++) acc[i][j] = zero;

    for (int k0 = 0; k0 < 512; k0 += 32) {
        short8 a[4], b[4];
#pragma unroll
        for (int i = 0; i < 4; i++)
            a[i] = *(const short8*)(A + (size_t)(m_base + m0 + i * 16 + l15) * 512 + k0 + quad * 8);
#pragma unroll
        for (int j = 0; j < 4; j++)
            b[j] = *(const short8*)(W + (size_t)(n0 + j * 16 + l15) * 512 + k0 + quad * 8);
#pragma unroll
        for (int i = 0; i < 4; i++)
#pragma unroll
            for (int j = 0; j < 4; j++)
                acc[i][j] = MFMA16(a[i], b[j], acc[i][j]);
    }

#pragma unroll
    for (int j = 0; j < 4; j++) {
        const int n = n0 + j * 16 + l15;
        const float bs = bias[n];
#pragma unroll
        for (int i = 0; i < 4; i++) {
#pragma unroll
            for (int r = 0; r < 4; r++) {
                const int m = m0 + i * 16 + quad * 4 + r;
                dst[(size_t)m * 512 + n] = acc[i][j][r] + bs;
            }
        }
    }
}

// ---------------------------------------------------------------------------
// Memory plan (ws >= 25 MB, proven rounds 8-9):
//   d_out [0,8M):    xb -> PO0 (flash split 0) -> proj0 output
//   d_out [8M,9.5M): wb (dead once flash writes PO1)
//   d_out [8M,16M):  PO1 / attn (combine in-place) -> proj1 output (copy)
//   ws [0,8M) Qf (later proj1 stage) | [8M,16M) Kf | [16M,24M) Vf
//   ws [24M,24.5M) lbuf | [24.5M,25M) pwb
// ---------------------------------------------------------------------------
extern "C" void kernel_launch(void* const* d_in, const int* in_sizes, int n_in,
                              void* d_out, int out_size, void* d_ws, size_t ws_size,
                              hipStream_t stream)
{
    const float* x      = (const float*)d_in[0];   // [2,4096,512] f32
    const float* qkv_w  = (const float*)d_in[1];   // [1536,512]   f32
    const float* qkv_b  = (const float*)d_in[2];   // [1536]       f32
    const float* proj_w = (const float*)d_in[3];   // [512,512]    f32
    const float* proj_b = (const float*)d_in[4];   // [512]        f32

    const size_t MB = 1024 * 1024;
    short* xb   = (short*)d_out;
    short* wb   = (short*)d_out + 4 * MB;
    short* attn = (short*)d_out + 4 * MB;
    float* out  = (float*)d_out;

    short* Qf = (short*)d_ws;
    short* Kf = Qf + (size_t)16 * 4096 * 64;
    short* Vf = Kf + (size_t)16 * 4096 * 64;       // [bh][64][4096]
    float* lbuf = (float*)((char*)d_ws + 24 * MB);
    short* pwb  = (short*)((char*)d_ws + 24 * MB + 512 * 1024);

    cvt3<<<2560, 256, 0, stream>>>(x, xb, 524288, qkv_w, wb, 98304, proj_w, pwb, 32768);
    qkv_qk<<<dim3(64, 8), 256, 0, stream>>>(xb, wb, qkv_b, Qf, Kf);
    qkv_v <<<dim3(64, 4), 256, 0, stream>>>(xb, wb, qkv_b, Vf);
    flash_attn<<<dim3(32, 16, 2), 256, 0, stream>>>(Qf, Kf, Vf, (short*)d_out, attn, lbuf, 32);
    combine<<<2048, 256, 0, stream>>>((const short*)d_out, attn, lbuf);
    proj_piece<<<dim3(32, 4), 256, 0, stream>>>(attn, pwb, proj_b, out, 0);
    proj_piece<<<dim3(32, 4), 256, 0, stream>>>(attn, pwb, proj_b, (float*)d_ws, 4096);
    hipMemcpyAsync((char*)d_out + 8 * MB, d_ws, 8 * MB,
                   hipMemcpyDeviceToDevice, stream);
}